// Round 6
// baseline (1432.662 us; speedup 1.0000x reference)
//
#include <hip/hip_runtime.h>

// GlobalNet conv-GRU on MI355X — round 6.
// vs r5: block reshaped 32m x 480n -> 64m x 240n (j-half), grid 128 x 2 = 256.
// Halves per-step B-fragment L2 traffic (1.07 MB -> 525 KB per block), which was
// the structural bottleneck; mi-paired waves load identical B frags (L1 dedup).
// Wave = (mi, jt): 2 m-frags x 3 segments (r/z/n) for j in [jhalf*80+jt*16, +16).

#define Bn   16
#define Tn   64
#define Ln   512
#define Cn   64
#define Hn   150
#define G3   450
#define SW   160
#define HP   160    // padded hidden
#define KCH  25     // k-chunks (32) for h GEMM (K=800)
#define KCX  10     // k-chunks for x GEMM (K=320)
#define Mtot 8192   // Bn*Ln

typedef __bf16 bf16x8 __attribute__((ext_vector_type(8)));
typedef float  f32x4  __attribute__((ext_vector_type(4)));
typedef short  s16x4  __attribute__((ext_vector_type(4)));

__device__ inline short f2bf(float f) {
  unsigned u = __builtin_bit_cast(unsigned, f);
  u += 0x7fffu + ((u >> 16) & 1u);   // RNE (finite inputs)
  return (short)(u >> 16);
}

// Packed B layout: [nt (n/16)][kc][lane (quad*16+l16)][j (8)] shorts.
// Fragment element: B[k = kc*32+quad*8+j][n = nt*16+l16].
// n maps (seg=n/160, jl=n%160) -> orig col seg*150+jl (zero pad elsewhere).
__global__ __launch_bounds__(256) void pack_weights(const float* __restrict__ ki,
                                                    const float* __restrict__ kh,
                                                    short* __restrict__ Bx,
                                                    short* __restrict__ Bh) {
  int idx = blockIdx.x * 256 + threadIdx.x;
  if (idx < 32 * KCH * 512) {
    int j = idx & 7, lane = (idx >> 3) & 63;
    int rest = idx >> 9;
    int kc = rest % KCH, nt = rest / KCH;
    int quad = lane >> 4, l16 = lane & 15;
    int n = nt * 16 + l16, seg = n / SW, jl = n - seg * SW;
    int kk = kc / 5, jj = (kc - kk * 5) * 32 + quad * 8 + j;
    float v = (seg < 3 && jl < Hn && jj < Hn) ? kh[(kk * Hn + jj) * G3 + seg * Hn + jl] : 0.f;
    Bh[idx] = f2bf(v);
  } else {
    int r = idx - 32 * KCH * 512;
    if (r < 32 * KCX * 512) {
      int j = r & 7, lane = (r >> 3) & 63;
      int rest = r >> 9;
      int kc = rest % KCX, nt = rest / KCX;
      int quad = lane >> 4, l16 = lane & 15;
      int n = nt * 16 + l16, seg = n / SW, jl = n - seg * SW;
      int kk = kc / 2, cc = (kc - kk * 2) * 32 + quad * 8 + j;
      float v = (seg < 3 && jl < Hn) ? ki[(kk * Cn + cc) * G3 + seg * Hn + jl] : 0.f;
      Bx[r] = f2bf(v);
    }
  }
}

// Fully-fused recurrent step. Grid 256 = 128 m-blocks (64 rows) x 2 j-halves.
// 640 threads (10 waves): wave = (mi in {0,1}, jt in {0..4}); wave computes
// 2 m-frags x 3 segment n-tiles {jh*5+jt, +10, +20} + axn, K = 800(h) + 320(x).
__global__ __launch_bounds__(640)
void gru_step(const short* __restrict__ hbin, short* __restrict__ hbout,
              float* __restrict__ hf, const short* __restrict__ Bh,
              const short* __restrict__ Bx, const float* __restrict__ xs, int t) {
  __shared__ short awh[68 * 168];   // h window rows l0-2..l0+65, 160 ch (22.9 KB)
  __shared__ short awx[68 * 72];    // x window, 64 ch (9.8 KB)
  const int tid   = threadIdx.x;
  const int nhalf = blockIdx.x & 1;
  const int mblk  = blockIdx.x >> 1;
  const int bb    = mblk >> 3;
  const int l0    = (mblk & 7) * 64;

  for (int i = tid; i < 68 * 40; i += 640) {
    int r = i / 40, c4 = (i - r * 40) * 4;
    int l = l0 - 2 + r;
    s16x4 v = {0, 0, 0, 0};
    if (l >= 0 && l < Ln) v = *(const s16x4*)&hbin[((size_t)bb * Ln + l) * HP + c4];
    *(s16x4*)&awh[r * 168 + c4] = v;
  }
  for (int i = tid; i < 68 * 16; i += 640) {
    int r = i >> 4, c4 = (i & 15) * 4;
    int l = l0 - 2 + r;
    s16x4 v = {0, 0, 0, 0};
    if (l >= 0 && l < Ln) {
      f32x4 f = *(const f32x4*)&xs[(((size_t)bb * Tn + t) * Ln + l) * Cn + c4];
      v[0] = f2bf(f[0]); v[1] = f2bf(f[1]); v[2] = f2bf(f[2]); v[3] = f2bf(f[3]);
    }
    *(s16x4*)&awx[r * 72 + c4] = v;
  }
  __syncthreads();

  const int lane = tid & 63, w = tid >> 6;
  const int quad = lane >> 4, l16 = lane & 15;
  const int jt = w % 5, mi = w / 5;

  const short* Bph[3];
  const short* Bpx[3];
#pragma unroll
  for (int g = 0; g < 3; ++g) {
    const int nt = g * 10 + nhalf * 5 + jt;
    Bph[g] = Bh + (size_t)nt * (KCH * 512) + lane * 8;
    Bpx[g] = Bx + (size_t)nt * (KCX * 512) + lane * 8;
  }
  const int arh = (mi * 32 + l16) * 168 + quad * 8;
  const int arx = (mi * 32 + l16) * 72 + quad * 8;

  f32x4 acc[2][3] = {};   // r | z | n(h-part), 2 m-frags
  f32x4 axn[2] = {};      // n(x-part): n = tanh(iin + r*hin)

  // Prime x-phase B loads early (independent of the h loop — deep in flight).
  bf16x8 bx[3][3];
#pragma unroll
  for (int s = 0; s < 2; ++s)
#pragma unroll
    for (int g = 0; g < 3; ++g) bx[s][g] = *(const bf16x8*)(Bpx[g] + s * 512);

  bf16x8 bh[4][3];   // 4-stage rolling prefetch
#pragma unroll
  for (int s = 0; s < 3; ++s)
#pragma unroll
    for (int g = 0; g < 3; ++g) bh[s][g] = *(const bf16x8*)(Bph[g] + s * 512);

#pragma unroll
  for (int kc = 0; kc < KCH; ++kc) {
    const int cur = kc & 3;
    if (kc + 3 < KCH) {
      const int nxt = (kc + 3) & 3;
#pragma unroll
      for (int g = 0; g < 3; ++g)
        bh[nxt][g] = *(const bf16x8*)(Bph[g] + (kc + 3) * 512);
    }
    const int kk = kc / 5, jj = (kc - kk * 5) * 32;
    const short* ar = &awh[arh + kk * 168 + jj];
    bf16x8 a0 = *(const bf16x8*)(ar);
    bf16x8 a1 = *(const bf16x8*)(ar + 16 * 168);
#pragma unroll
    for (int g = 0; g < 3; ++g) {
      acc[0][g] = __builtin_amdgcn_mfma_f32_16x16x32_bf16(a0, bh[cur][g], acc[0][g], 0, 0, 0);
      acc[1][g] = __builtin_amdgcn_mfma_f32_16x16x32_bf16(a1, bh[cur][g], acc[1][g], 0, 0, 0);
    }
  }

#pragma unroll
  for (int kc = 0; kc < KCX; ++kc) {
    const int cur = kc % 3;
    if (kc + 2 < KCX) {
      const int nxt = (kc + 2) % 3;
#pragma unroll
      for (int g = 0; g < 3; ++g)
        bx[nxt][g] = *(const bf16x8*)(Bpx[g] + (kc + 2) * 512);
    }
    const int kk = kc >> 1, jj = (kc & 1) * 32;
    const short* ar = &awx[arx + kk * 72 + jj];
    bf16x8 a0 = *(const bf16x8*)(ar);
    bf16x8 a1 = *(const bf16x8*)(ar + 16 * 72);
    acc[0][0] = __builtin_amdgcn_mfma_f32_16x16x32_bf16(a0, bx[cur][0], acc[0][0], 0, 0, 0);
    acc[1][0] = __builtin_amdgcn_mfma_f32_16x16x32_bf16(a1, bx[cur][0], acc[1][0], 0, 0, 0);
    acc[0][1] = __builtin_amdgcn_mfma_f32_16x16x32_bf16(a0, bx[cur][1], acc[0][1], 0, 0, 0);
    acc[1][1] = __builtin_amdgcn_mfma_f32_16x16x32_bf16(a1, bx[cur][1], acc[1][1], 0, 0, 0);
    axn[0]    = __builtin_amdgcn_mfma_f32_16x16x32_bf16(a0, bx[cur][2], axn[0], 0, 0, 0);
    axn[1]    = __builtin_amdgcn_mfma_f32_16x16x32_bf16(a1, bx[cur][2], axn[1], 0, 0, 0);
  }

  // Gates: lane covers j = nhalf*80 + jt*16 + l16; m-rows mi*32 + f*16 + quad*4 + r.
  const int j = nhalf * 80 + jt * 16 + l16;
  if (j < Hn) {
#pragma unroll
    for (int f = 0; f < 2; ++f)
#pragma unroll
      for (int r = 0; r < 4; ++r) {
        const int ml = mi * 32 + f * 16 + quad * 4 + r;
        const size_t mrow = (size_t)bb * Ln + l0 + ml;
        float rg = 1.f / (1.f + __expf(-acc[f][0][r]));
        float zg = 1.f / (1.f + __expf(-acc[f][1][r]));
        float xg = axn[f][r] + rg * acc[f][2][r];
        xg = fminf(fmaxf(xg, -15.f), 15.f);
        float e = __expf(2.f * xg);
        float n = (e - 1.f) / (e + 1.f);
        float hn = (1.f - zg) * n + zg * hf[mrow * Hn + j];
        hf[mrow * Hn + j] = hn;
        hbout[mrow * HP + j] = f2bf(hn);
      }
  }
}

// Head: thread-per-output fp32.
__global__ __launch_bounds__(256) void head1(const float* __restrict__ hf,
                                             const float* __restrict__ W1,
                                             const float* __restrict__ b1,
                                             float* __restrict__ hdn) {
  int idx = blockIdx.x * 256 + threadIdx.x;
  if (idx >= Mtot * Hn) return;
  int m = idx / Hn, j = idx - m * Hn;
  const float* hr = hf + (size_t)m * Hn;
  float acc = b1[j];
#pragma unroll 10
  for (int i = 0; i < Hn; ++i) acc = fmaf(hr[i], W1[i * Hn + j], acc);
  hdn[idx] = acc / (1.f + __expf(-acc));   // silu
}
__global__ __launch_bounds__(256) void head2(const float* __restrict__ hdn,
                                             const float* __restrict__ W2,
                                             const float* __restrict__ b2,
                                             float* __restrict__ out) {
  int idx = blockIdx.x * 256 + threadIdx.x;
  if (idx >= Mtot * 24) return;
  int m = idx / 24, j = idx - m * 24;
  const float* hr = hdn + (size_t)m * Hn;
  float acc = b2[j];
#pragma unroll 10
  for (int i = 0; i < Hn; ++i) acc = fmaf(hr[i], W2[i * 24 + j], acc);
  out[idx] = acc;
}

extern "C" void kernel_launch(void* const* d_in, const int* in_sizes, int n_in,
                              void* d_out, int out_size, void* d_ws, size_t ws_size,
                              hipStream_t stream) {
  const float* xs = (const float*)d_in[0];
  const float* ki = (const float*)d_in[1];
  const float* kh = (const float*)d_in[2];
  const float* W1 = (const float*)d_in[3];
  const float* b1 = (const float*)d_in[4];
  const float* W2 = (const float*)d_in[5];
  const float* b2 = (const float*)d_in[6];
  float* out = (float*)d_out;

  char* p = (char*)d_ws;
  float* hf  = (float*)p; p += (size_t)Mtot * Hn * 4;       // 4.7 MiB
  float* hdn = (float*)p; p += (size_t)Mtot * Hn * 4;       // 4.7 MiB
  short* hbA = (short*)p; p += (size_t)Mtot * HP * 2;       // 2.5 MiB
  short* hbB = (short*)p; p += (size_t)Mtot * HP * 2;       // 2.5 MiB
  short* Bh  = (short*)p; p += (size_t)32 * KCH * 512 * 2;  // 0.8 MiB
  short* Bx  = (short*)p; p += (size_t)32 * KCX * 512 * 2;  // 0.3 MiB

  hipMemsetAsync(hf, 0, (size_t)Mtot * Hn * 4, stream);
  hipMemsetAsync(hbA, 0, (size_t)Mtot * HP * 2 * 2, stream);  // both buffers; pads stay 0
  pack_weights<<<(32 * (KCH + KCX) * 512 + 255) / 256, 256, 0, stream>>>(ki, kh, Bx, Bh);

  for (int t = 0; t < Tn; ++t) {
    short* hin  = (t & 1) ? hbB : hbA;
    short* hout = (t & 1) ? hbA : hbB;
    gru_step<<<256, 640, 0, stream>>>(hin, hout, hf, Bh, Bx, xs, t);
  }
  head1<<<(Mtot * Hn + 255) / 256, 256, 0, stream>>>(hf, W1, b1, hdn);
  head2<<<(Mtot * 24 + 255) / 256, 256, 0, stream>>>(hdn, W2, b2, out);
}

// Round 7
// 1424.672 us; speedup vs baseline: 1.0056x; 1.0056x over previous
//
#include <hip/hip_runtime.h>

// GlobalNet conv-GRU on MI355X — round 7.
// r6 post-mortem: r5 was L2-LATENCY-bound (1.8 TB/s/XCD << 4.3 ceiling), not
// BW-bound; r6's dedup attacked the wrong constraint and doubled staging.
// r7 = r5 structure with latency fixes: two independent 320-thr blocks per CU
// (grid 512 = 256 m-blocks x 2 j-halves; co-resident block fills stalls), and
// 5-stage h-prefetch (lead ~360 wall-cyc > L2 latency ~200-300).

#define Bn   16
#define Tn   64
#define Ln   512
#define Cn   64
#define Hn   150
#define G3   450
#define SW   160
#define HP   160    // padded hidden
#define KCH  25     // k-chunks (32) for h GEMM (K=800)
#define KCX  10     // k-chunks for x GEMM (K=320)
#define Mtot 8192   // Bn*Ln

typedef __bf16 bf16x8 __attribute__((ext_vector_type(8)));
typedef float  f32x4  __attribute__((ext_vector_type(4)));
typedef short  s16x4  __attribute__((ext_vector_type(4)));

__device__ inline short f2bf(float f) {
  unsigned u = __builtin_bit_cast(unsigned, f);
  u += 0x7fffu + ((u >> 16) & 1u);   // RNE (finite inputs)
  return (short)(u >> 16);
}

// Packed B layout: [nt (n/16)][kc][lane (quad*16+l16)][j (8)] shorts.
// Fragment element: B[k = kc*32+quad*8+j][n = nt*16+l16].
// n maps (seg=n/160, jl=n%160) -> orig col seg*150+jl (zero pad elsewhere).
__global__ __launch_bounds__(256) void pack_weights(const float* __restrict__ ki,
                                                    const float* __restrict__ kh,
                                                    short* __restrict__ Bx,
                                                    short* __restrict__ Bh) {
  int idx = blockIdx.x * 256 + threadIdx.x;
  if (idx < 32 * KCH * 512) {
    int j = idx & 7, lane = (idx >> 3) & 63;
    int rest = idx >> 9;
    int kc = rest % KCH, nt = rest / KCH;
    int quad = lane >> 4, l16 = lane & 15;
    int n = nt * 16 + l16, seg = n / SW, jl = n - seg * SW;
    int kk = kc / 5, jj = (kc - kk * 5) * 32 + quad * 8 + j;
    float v = (seg < 3 && jl < Hn && jj < Hn) ? kh[(kk * Hn + jj) * G3 + seg * Hn + jl] : 0.f;
    Bh[idx] = f2bf(v);
  } else {
    int r = idx - 32 * KCH * 512;
    if (r < 32 * KCX * 512) {
      int j = r & 7, lane = (r >> 3) & 63;
      int rest = r >> 9;
      int kc = rest % KCX, nt = rest / KCX;
      int quad = lane >> 4, l16 = lane & 15;
      int n = nt * 16 + l16, seg = n / SW, jl = n - seg * SW;
      int kk = kc / 2, cc = (kc - kk * 2) * 32 + quad * 8 + j;
      float v = (seg < 3 && jl < Hn) ? ki[(kk * Cn + cc) * G3 + seg * Hn + jl] : 0.f;
      Bx[r] = f2bf(v);
    }
  }
}

// Fully-fused recurrent step. Grid 512 = 256 m-blocks (32 rows) x 2 j-halves.
// 320 threads (5 waves); wave w = jt covers 2 m-frags x 3 segment n-tiles
// {nhalf*5+w, +10, +20} + axn. K = 800(h) + 320(x). 2 blocks co-resident/CU.
__global__ __launch_bounds__(320, 3)
void gru_step(const short* __restrict__ hbin, short* __restrict__ hbout,
              float* __restrict__ hf, const short* __restrict__ Bh,
              const short* __restrict__ Bx, const float* __restrict__ xs, int t) {
  __shared__ short awh[36 * 168];   // h window rows l0-2..l0+33, 160 ch (12.1 KB)
  __shared__ short awx[36 * 72];    // x window, 64 ch (5.2 KB)
  const int tid   = threadIdx.x;
  const int nhalf = blockIdx.x & 1;
  const int mblk  = blockIdx.x >> 1;
  const int bb    = mblk >> 4;
  const int l0    = (mblk & 15) * 32;

  for (int i = tid; i < 36 * 40; i += 320) {
    int r = i / 40, c4 = (i - r * 40) * 4;
    int l = l0 - 2 + r;
    s16x4 v = {0, 0, 0, 0};
    if (l >= 0 && l < Ln) v = *(const s16x4*)&hbin[((size_t)bb * Ln + l) * HP + c4];
    *(s16x4*)&awh[r * 168 + c4] = v;
  }
  for (int i = tid; i < 36 * 16; i += 320) {
    int r = i >> 4, c4 = (i & 15) * 4;
    int l = l0 - 2 + r;
    s16x4 v = {0, 0, 0, 0};
    if (l >= 0 && l < Ln) {
      f32x4 f = *(const f32x4*)&xs[(((size_t)bb * Tn + t) * Ln + l) * Cn + c4];
      v[0] = f2bf(f[0]); v[1] = f2bf(f[1]); v[2] = f2bf(f[2]); v[3] = f2bf(f[3]);
    }
    *(s16x4*)&awx[r * 72 + c4] = v;
  }
  __syncthreads();

  const int lane = tid & 63, w = tid >> 6;   // w = jt in 0..4
  const int quad = lane >> 4, l16 = lane & 15;

  const short* Bph[3];
  const short* Bpx[3];
#pragma unroll
  for (int g = 0; g < 3; ++g) {
    const int nt = g * 10 + nhalf * 5 + w;
    Bph[g] = Bh + (size_t)nt * (KCH * 512) + lane * 8;
    Bpx[g] = Bx + (size_t)nt * (KCX * 512) + lane * 8;
  }
  const int arh = l16 * 168 + quad * 8;
  const int arx = l16 * 72 + quad * 8;

  f32x4 acc[2][3] = {};   // r | z | n(h-part), 2 m-frags
  f32x4 axn[2] = {};      // n(x-part): n = tanh(iin + r*hin)

  // Prime x-phase B loads early (independent of the h loop — deep in flight).
  bf16x8 bx[3][3];
#pragma unroll
  for (int s = 0; s < 2; ++s)
#pragma unroll
    for (int g = 0; g < 3; ++g) bx[s][g] = *(const bf16x8*)(Bpx[g] + s * 512);

  bf16x8 bh[5][3];   // 5-stage rolling prefetch (lead ~5 kc > L2 latency)
#pragma unroll
  for (int s = 0; s < 4; ++s)
#pragma unroll
    for (int g = 0; g < 3; ++g) bh[s][g] = *(const bf16x8*)(Bph[g] + s * 512);

#pragma unroll
  for (int kc = 0; kc < KCH; ++kc) {
    const int cur = kc % 5;
    if (kc + 4 < KCH) {
      const int nxt = (kc + 4) % 5;
#pragma unroll
      for (int g = 0; g < 3; ++g)
        bh[nxt][g] = *(const bf16x8*)(Bph[g] + (kc + 4) * 512);
    }
    const int kk = kc / 5, jj = (kc - kk * 5) * 32;
    const short* ar = &awh[arh + kk * 168 + jj];
    bf16x8 a0 = *(const bf16x8*)(ar);
    bf16x8 a1 = *(const bf16x8*)(ar + 16 * 168);
#pragma unroll
    for (int g = 0; g < 3; ++g) {
      acc[0][g] = __builtin_amdgcn_mfma_f32_16x16x32_bf16(a0, bh[cur][g], acc[0][g], 0, 0, 0);
      acc[1][g] = __builtin_amdgcn_mfma_f32_16x16x32_bf16(a1, bh[cur][g], acc[1][g], 0, 0, 0);
    }
  }

#pragma unroll
  for (int kc = 0; kc < KCX; ++kc) {
    const int cur = kc % 3;
    if (kc + 2 < KCX) {
      const int nxt = (kc + 2) % 3;
#pragma unroll
      for (int g = 0; g < 3; ++g)
        bx[nxt][g] = *(const bf16x8*)(Bpx[g] + (kc + 2) * 512);
    }
    const int kk = kc >> 1, jj = (kc & 1) * 32;
    const short* ar = &awx[arx + kk * 72 + jj];
    bf16x8 a0 = *(const bf16x8*)(ar);
    bf16x8 a1 = *(const bf16x8*)(ar + 16 * 72);
    acc[0][0] = __builtin_amdgcn_mfma_f32_16x16x32_bf16(a0, bx[cur][0], acc[0][0], 0, 0, 0);
    acc[1][0] = __builtin_amdgcn_mfma_f32_16x16x32_bf16(a1, bx[cur][0], acc[1][0], 0, 0, 0);
    acc[0][1] = __builtin_amdgcn_mfma_f32_16x16x32_bf16(a0, bx[cur][1], acc[0][1], 0, 0, 0);
    acc[1][1] = __builtin_amdgcn_mfma_f32_16x16x32_bf16(a1, bx[cur][1], acc[1][1], 0, 0, 0);
    axn[0]    = __builtin_amdgcn_mfma_f32_16x16x32_bf16(a0, bx[cur][2], axn[0], 0, 0, 0);
    axn[1]    = __builtin_amdgcn_mfma_f32_16x16x32_bf16(a1, bx[cur][2], axn[1], 0, 0, 0);
  }

  // Gates: lane covers j = nhalf*80 + w*16 + l16; m-rows mi*16 + quad*4 + r.
  const int j = nhalf * 80 + w * 16 + l16;
  if (j < Hn) {
#pragma unroll
    for (int mi = 0; mi < 2; ++mi)
#pragma unroll
      for (int r = 0; r < 4; ++r) {
        const int ml = mi * 16 + quad * 4 + r;
        const size_t mrow = (size_t)bb * Ln + l0 + ml;
        float rg = 1.f / (1.f + __expf(-acc[mi][0][r]));
        float zg = 1.f / (1.f + __expf(-acc[mi][1][r]));
        float xg = axn[mi][r] + rg * acc[mi][2][r];
        xg = fminf(fmaxf(xg, -15.f), 15.f);
        float e = __expf(2.f * xg);
        float n = (e - 1.f) / (e + 1.f);
        float hn = (1.f - zg) * n + zg * hf[mrow * Hn + j];
        hf[mrow * Hn + j] = hn;
        hbout[mrow * HP + j] = f2bf(hn);
      }
  }
}

// Head: thread-per-output fp32.
__global__ __launch_bounds__(256) void head1(const float* __restrict__ hf,
                                             const float* __restrict__ W1,
                                             const float* __restrict__ b1,
                                             float* __restrict__ hdn) {
  int idx = blockIdx.x * 256 + threadIdx.x;
  if (idx >= Mtot * Hn) return;
  int m = idx / Hn, j = idx - m * Hn;
  const float* hr = hf + (size_t)m * Hn;
  float acc = b1[j];
#pragma unroll 10
  for (int i = 0; i < Hn; ++i) acc = fmaf(hr[i], W1[i * Hn + j], acc);
  hdn[idx] = acc / (1.f + __expf(-acc));   // silu
}
__global__ __launch_bounds__(256) void head2(const float* __restrict__ hdn,
                                             const float* __restrict__ W2,
                                             const float* __restrict__ b2,
                                             float* __restrict__ out) {
  int idx = blockIdx.x * 256 + threadIdx.x;
  if (idx >= Mtot * 24) return;
  int m = idx / 24, j = idx - m * 24;
  const float* hr = hdn + (size_t)m * Hn;
  float acc = b2[j];
#pragma unroll 10
  for (int i = 0; i < Hn; ++i) acc = fmaf(hr[i], W2[i * 24 + j], acc);
  out[idx] = acc;
}

extern "C" void kernel_launch(void* const* d_in, const int* in_sizes, int n_in,
                              void* d_out, int out_size, void* d_ws, size_t ws_size,
                              hipStream_t stream) {
  const float* xs = (const float*)d_in[0];
  const float* ki = (const float*)d_in[1];
  const float* kh = (const float*)d_in[2];
  const float* W1 = (const float*)d_in[3];
  const float* b1 = (const float*)d_in[4];
  const float* W2 = (const float*)d_in[5];
  const float* b2 = (const float*)d_in[6];
  float* out = (float*)d_out;

  char* p = (char*)d_ws;
  float* hf  = (float*)p; p += (size_t)Mtot * Hn * 4;       // 4.7 MiB
  float* hdn = (float*)p; p += (size_t)Mtot * Hn * 4;       // 4.7 MiB
  short* hbA = (short*)p; p += (size_t)Mtot * HP * 2;       // 2.5 MiB
  short* hbB = (short*)p; p += (size_t)Mtot * HP * 2;       // 2.5 MiB
  short* Bh  = (short*)p; p += (size_t)32 * KCH * 512 * 2;  // 0.8 MiB
  short* Bx  = (short*)p; p += (size_t)32 * KCX * 512 * 2;  // 0.3 MiB

  hipMemsetAsync(hf, 0, (size_t)Mtot * Hn * 4, stream);
  hipMemsetAsync(hbA, 0, (size_t)Mtot * HP * 2 * 2, stream);  // both buffers; pads stay 0
  pack_weights<<<(32 * (KCH + KCX) * 512 + 255) / 256, 256, 0, stream>>>(ki, kh, Bx, Bh);

  for (int t = 0; t < Tn; ++t) {
    short* hin  = (t & 1) ? hbB : hbA;
    short* hout = (t & 1) ? hbA : hbB;
    gru_step<<<512, 320, 0, stream>>>(hin, hout, hf, Bh, Bx, xs, t);
  }
  head1<<<(Mtot * Hn + 255) / 256, 256, 0, stream>>>(hf, W1, b1, hdn);
  head2<<<(Mtot * 24 + 255) / 256, 256, 0, stream>>>(hdn, W2, b2, out);
}